// Round 1
// baseline (309.749 us; speedup 1.0000x reference)
//
#include <hip/hip_runtime.h>
#include <hip/hip_bf16.h>
#include <math.h>

// Problem constants (fixed by setup_inputs)
#define B 8
#define R 4096
#define C 1024
#define NROWS (B * R)          // 32768
#define F4_PER_ROW (C / 4)     // 256

// ---------------------------------------------------------------------------
// Kernel 1: keep_fraction = sigmoid(logits[b] . score_w + score_b)
//           k[b] = clamp((int)(kf * R), 1, R)
// 8 blocks (one per batch), 256 threads. Double accumulation for stability.
// ---------------------------------------------------------------------------
__global__ void k_score(const float* __restrict__ logits,
                        const float* __restrict__ sw,
                        const float* __restrict__ sb,
                        int* __restrict__ d_k) {
    int b = blockIdx.x;
    int t = threadIdx.x;
    double acc = 0.0;
    for (int i = t; i < C; i += 256)
        acc += (double)logits[b * C + i] * (double)sw[i];
    // wave64 shuffle reduce
    for (int off = 32; off > 0; off >>= 1)
        acc += __shfl_down(acc, off, 64);
    __shared__ double ssum[4];
    int wave = t >> 6, lane = t & 63;
    if (lane == 0) ssum[wave] = acc;
    __syncthreads();
    if (t == 0) {
        double s = ssum[0] + ssum[1] + ssum[2] + ssum[3] + (double)sb[0];
        double kf = 1.0 / (1.0 + exp(-s));
        int k = (int)(kf * (double)R);   // truncation, kf >= 0
        if (k < 1) k = 1;
        if (k > R) k = R;
        d_k[b] = k;
    }
}

// ---------------------------------------------------------------------------
// Kernel 2: row_magnitudes[row] = ||weight_params[row, :]||_2
// One wave (64 lanes) per row; 4 waves per block -> 8192 blocks.
// float4 coalesced loads, double accumulation (ordering fidelity near the
// k-th order statistic).
// ---------------------------------------------------------------------------
__global__ void k_mags(const float* __restrict__ wp,
                       float* __restrict__ mags) {
    int row  = blockIdx.x * 4 + (threadIdx.x >> 6);
    int lane = threadIdx.x & 63;
    const float4* p = (const float4*)(wp + (size_t)row * C);
    double acc = 0.0;
#pragma unroll
    for (int j = 0; j < 4; ++j) {
        float4 v = p[j * 64 + lane];
        acc += (double)v.x * v.x + (double)v.y * v.y +
               (double)v.z * v.z + (double)v.w * v.w;
    }
    for (int off = 32; off > 0; off >>= 1)
        acc += __shfl_down(acc, off, 64);
    if (lane == 0) mags[row] = (float)sqrt(acc);
}

// ---------------------------------------------------------------------------
// Kernel 3: per batch, bitonic-sort the 4096 magnitudes descending in LDS,
// threshold = sorted[k-1]. 8 blocks x 1024 threads, 16 KiB LDS.
// ---------------------------------------------------------------------------
__global__ void k_thresh(const float* __restrict__ mags,
                         const int* __restrict__ d_k,
                         float* __restrict__ thr) {
    __shared__ float sm[R];
    int b = blockIdx.x, t = threadIdx.x;
    for (int i = t; i < R; i += 1024)
        sm[i] = mags[b * R + i];
    __syncthreads();
    for (int k = 2; k <= R; k <<= 1) {
        for (int j = k >> 1; j > 0; j >>= 1) {
            for (int i = t; i < R; i += 1024) {
                int ixj = i ^ j;
                if (ixj > i) {
                    float a = sm[i], c = sm[ixj];
                    bool desc = ((i & k) == 0);
                    if (desc ? (a < c) : (a > c)) { sm[i] = c; sm[ixj] = a; }
                }
            }
            __syncthreads();
        }
    }
    if (t == 0) thr[b] = sm[d_k[b] - 1];
}

// ---------------------------------------------------------------------------
// Kernel 4: out = wp * (mags[row] >= thr[batch] ? 1 : 0), float4 streaming.
// 8M float4 elements -> 32768 blocks x 256 threads.
// ---------------------------------------------------------------------------
__global__ void k_apply(const float* __restrict__ wp,
                        const float* __restrict__ mags,
                        const float* __restrict__ thr,
                        float* __restrict__ out) {
    size_t g = (size_t)blockIdx.x * blockDim.x + threadIdx.x;  // float4 index
    int row = (int)(g >> 8);       // 256 float4 per row
    int b   = row >> 12;           // 4096 rows per batch
    float m = (mags[row] >= thr[b]) ? 1.0f : 0.0f;
    float4 v = ((const float4*)wp)[g];
    v.x *= m; v.y *= m; v.z *= m; v.w *= m;
    ((float4*)out)[g] = v;
}

extern "C" void kernel_launch(void* const* d_in, const int* in_sizes, int n_in,
                              void* d_out, int out_size, void* d_ws, size_t ws_size,
                              hipStream_t stream) {
    const float* wp     = (const float*)d_in[0];  // [8,4096,1024]
    const float* logits = (const float*)d_in[1];  // [8,1024]
    const float* sw     = (const float*)d_in[2];  // [1024,1]
    const float* sb     = (const float*)d_in[3];  // [1]
    float* out = (float*)d_out;

    // Workspace layout: mags (32768 f32 = 128 KiB) | thr (8 f32) | k (8 i32)
    float* mags = (float*)d_ws;
    float* thr  = mags + NROWS;
    int*   dk   = (int*)(thr + B);

    k_score<<<B, 256, 0, stream>>>(logits, sw, sb, dk);
    k_mags<<<NROWS / 4, 256, 0, stream>>>(wp, mags);
    k_thresh<<<B, 1024, 0, stream>>>(mags, dk, thr);
    k_apply<<<(NROWS * F4_PER_ROW) / 256, 256, 0, stream>>>(wp, mags, thr, out);
}

// Round 2
// 250.569 us; speedup vs baseline: 1.2362x; 1.2362x over previous
//
#include <hip/hip_runtime.h>
#include <hip/hip_bf16.h>
#include <math.h>

// Problem constants (fixed by setup_inputs)
#define B 8
#define R 4096
#define C 1024
#define NROWS (B * R)          // 32768
#define F4_PER_ROW (C / 4)     // 256

// ---------------------------------------------------------------------------
// Kernel 1: row_magnitudes[row] = ||weight_params[row, :]||_2
// One wave per row, 4 waves/block -> 8192 blocks. float4 loads, double acc
// (ordering fidelity near the k-th order statistic; R1 passed absmax=0.0).
// ---------------------------------------------------------------------------
__global__ void k_mags(const float* __restrict__ wp,
                       float* __restrict__ mags) {
    int row  = blockIdx.x * 4 + (threadIdx.x >> 6);
    int lane = threadIdx.x & 63;
    const float4* p = (const float4*)(wp + (size_t)row * C);
    double acc = 0.0;
#pragma unroll
    for (int j = 0; j < 4; ++j) {
        float4 v = p[j * 64 + lane];
        acc += (double)v.x * v.x + (double)v.y * v.y +
               (double)v.z * v.z + (double)v.w * v.w;
    }
    for (int off = 32; off > 0; off >>= 1)
        acc += __shfl_down(acc, off, 64);
    if (lane == 0) mags[row] = (float)sqrt(acc);
}

// ---------------------------------------------------------------------------
// Kernel 2: per batch (8 blocks x 1024 threads):
//   Phase 0: k = clamp(int(sigmoid(logits[b].sw + sb) * R), 1, R)
//   Phase 1-4: 4-pass radix select (8 bits/pass) over the 4096 row norms'
//   u32 bit patterns (non-negative floats are order-isomorphic to u32) to
//   find the exact k-th largest value. Elements stay in registers; 256-bin
//   LDS histogram + single-wave Kogge-Stone suffix scan per pass.
// Replaces the 78-phase bitonic sort (the ~230us latency-bound tail of R1).
// ---------------------------------------------------------------------------
__global__ void k_select(const float* __restrict__ logits,
                         const float* __restrict__ sw,
                         const float* __restrict__ sb,
                         const float* __restrict__ mags,
                         float* __restrict__ thr) {
    __shared__ unsigned hist[256];
    __shared__ double dred[16];
    __shared__ unsigned sh_prefix;
    __shared__ int sh_krem;

    const int b = blockIdx.x, t = threadIdx.x;
    const int wave = t >> 6, lane = t & 63;

    // ---- Phase 0: rows_to_keep -------------------------------------------
    double a = (double)logits[b * C + t] * (double)sw[t];
    for (int off = 32; off > 0; off >>= 1)
        a += __shfl_down(a, off, 64);
    if (lane == 0) dred[wave] = a;
    __syncthreads();
    if (t == 0) {
        double s = (double)sb[0];
        for (int w = 0; w < 16; ++w) s += dred[w];
        double kf = 1.0 / (1.0 + exp(-s));
        int k = (int)(kf * (double)R);   // truncation, kf >= 0
        if (k < 1) k = 1;
        if (k > R) k = R;
        sh_krem = k;
        sh_prefix = 0u;
    }

    // ---- load this batch's norms into registers as sortable u32 ----------
    unsigned u[4];
#pragma unroll
    for (int j = 0; j < 4; ++j)
        u[j] = __float_as_uint(mags[b * R + t + j * 1024]);
    __syncthreads();   // sh_krem/sh_prefix visible

    // ---- Phase 1-4: radix select, high byte -> low byte -------------------
    const int shifts[4] = {24, 16, 8, 0};
    const unsigned maskH[4] = {0x00000000u, 0xFF000000u, 0xFFFF0000u, 0xFFFFFF00u};
#pragma unroll
    for (int p = 0; p < 4; ++p) {
        const int shift = shifts[p];
        const unsigned mh = maskH[p];
        if (t < 256) hist[t] = 0u;
        __syncthreads();
        const unsigned pref = sh_prefix;
        const int krem = sh_krem;
#pragma unroll
        for (int j = 0; j < 4; ++j) {
            if ((u[j] & mh) == pref)
                atomicAdd(&hist[(u[j] >> shift) & 255u], 1u);
        }
        __syncthreads();
        if (t < 64) {  // wave 0: suffix scan over 256 bins, 4 bins/lane
            unsigned h0 = hist[4 * t], h1 = hist[4 * t + 1],
                     h2 = hist[4 * t + 2], h3 = hist[4 * t + 3];
            unsigned s4 = h0 + h1 + h2 + h3;
            unsigned suf = s4;
            for (int off = 1; off < 64; off <<= 1) {
                unsigned tmp = __shfl_down(suf, off, 64);
                if (lane + off < 64) suf += tmp;
            }
            unsigned below = suf - s4;  // count in bins strictly above this group
            if ((int)suf >= krem && (int)below < krem) {
                // the k-th largest lives in this lane's 4 bins
                unsigned hh[4] = {h0, h1, h2, h3};
                unsigned cum = below;
                for (int bb = 3; bb >= 0; --bb) {
                    cum += hh[bb];
                    if ((int)cum >= krem) {
                        sh_krem   = krem - (int)(cum - hh[bb]);
                        sh_prefix = pref | ((unsigned)(4 * t + bb) << shift);
                        break;
                    }
                }
            }
        }
        __syncthreads();
    }
    if (t == 0) thr[b] = __uint_as_float(sh_prefix);
}

// ---------------------------------------------------------------------------
// Kernel 3: out = wp * (mags[row] >= thr[batch]), float4 streaming.
// Nontemporal stores: keep wp resident in L3 instead of output.
// ---------------------------------------------------------------------------
__global__ void k_apply(const float* __restrict__ wp,
                        const float* __restrict__ mags,
                        const float* __restrict__ thr,
                        float* __restrict__ out) {
    size_t g = (size_t)blockIdx.x * blockDim.x + threadIdx.x;  // float4 index
    int row = (int)(g >> 8);       // 256 float4 per row
    int b   = row >> 12;           // 4096 rows per batch
    float m = (mags[row] >= thr[b]) ? 1.0f : 0.0f;
    float4 v = ((const float4*)wp)[g];
    v.x *= m; v.y *= m; v.z *= m; v.w *= m;
    float4* o = ((float4*)out) + g;
    __builtin_nontemporal_store(v.x, &o->x);
    __builtin_nontemporal_store(v.y, &o->y);
    __builtin_nontemporal_store(v.z, &o->z);
    __builtin_nontemporal_store(v.w, &o->w);
}

extern "C" void kernel_launch(void* const* d_in, const int* in_sizes, int n_in,
                              void* d_out, int out_size, void* d_ws, size_t ws_size,
                              hipStream_t stream) {
    const float* wp     = (const float*)d_in[0];  // [8,4096,1024]
    const float* logits = (const float*)d_in[1];  // [8,1024]
    const float* sw     = (const float*)d_in[2];  // [1024,1]
    const float* sb     = (const float*)d_in[3];  // [1]
    float* out = (float*)d_out;

    // Workspace: mags (32768 f32 = 128 KiB) | thr (8 f32)
    float* mags = (float*)d_ws;
    float* thr  = mags + NROWS;

    k_mags  <<<NROWS / 4, 256, 0, stream>>>(wp, mags);
    k_select<<<B, 1024, 0, stream>>>(logits, sw, sb, mags, thr);
    k_apply <<<(NROWS * F4_PER_ROW) / 256, 256, 0, stream>>>(wp, mags, thr, out);
}